// Round 1
// 222.246 us; speedup vs baseline: 1.1223x; 1.1223x over previous
//
#include <hip/hip_runtime.h>

#define NEG_SLOPE 0.01f
#define EPB 4096          // edges per block in bucket build
#define NB_SHIFT 8        // 256 dst-nodes per bucket

typedef __attribute__((ext_vector_type(8))) short bf16x8;
typedef __attribute__((ext_vector_type(4))) float floatx4;

__device__ __forceinline__ short f2bf(float f) {
    union { float f; unsigned u; } v; v.f = f;
    unsigned u = v.u;
    u += 0x7FFF + ((u >> 16) & 1);          // round-to-nearest-even
    return (short)(u >> 16);
}
__device__ __forceinline__ float bf2f(short s) {
    union { unsigned u; float f; } v;
    v.u = ((unsigned)(unsigned short)s) << 16;
    return v.f;
}

// ================= K1: per-block bucket histogram -> atomic btot, + weight pack =================
// blocks [0,B): per-4096-edge dst-bucket histogram accumulated into btot[K] (global atomics,
//   one per (block,bucket) -- ~38k total).
// blocks [B,B+192): pack W1 (K=256) then [Wmu|Wlv] (K=128) into MFMA frag order:
//   flat = (kb*8+t)*512 + lane*8 + j  holds  W[kb*32+q*8+j][t*16+ln], lane=q*16+ln.

__launch_bounds__(256)
__global__ void hist_pack(const int* __restrict__ dst, int E, int B, int K,
                          int* __restrict__ btot,
                          const float* __restrict__ W1, const float* __restrict__ Wmu,
                          const float* __restrict__ Wlv,
                          short* __restrict__ w1f, short* __restrict__ wcatf) {
    __shared__ int lh[256];
    int bid = blockIdx.x;
    if (bid < B) {
        lh[threadIdx.x] = 0;
        __syncthreads();
        int lo = bid * EPB, hi = min(lo + EPB, E);
        for (int e = lo + threadIdx.x; e < hi; e += 256)
            atomicAdd(&lh[dst[e] >> NB_SHIFT], 1);
        __syncthreads();
        int v = lh[threadIdx.x];
        if (v) atomicAdd(&btot[threadIdx.x], v);
    } else {
        int i = (bid - B) * 256 + threadIdx.x;
        if (i < 128 * 256) {
            int j  = i & 7;
            int ln = (i >> 3) & 15;
            int q  = (i >> 7) & 3;
            int t  = (i >> 9) & 7;
            int kb = i >> 12;
            int n = t * 16 + ln;
            int k = kb * 32 + q * 8 + j;
            w1f[i] = f2bf(W1[k * 128 + n]);
        } else {
            int i2 = i - 128 * 256;
            int j  = i2 & 7;
            int ln = (i2 >> 3) & 15;
            int q  = (i2 >> 7) & 3;
            int t  = (i2 >> 9) & 7;
            int kb = i2 >> 12;
            int n = t * 16 + ln;
            int k = kb * 32 + q * 8 + j;
            wcatf[i2] = f2bf((n < 64) ? Wmu[k * 64 + n] : Wlv[k * 64 + (n - 64)]);
        }
    }
}

// one block: exclusive scan of btot[K] -> bstart[0..K] (bstart[K]=E), init bcur = bstart.
// K <= 256 guaranteed (u16 csr requires N < 65536).
__global__ void bucket_scan(const int* __restrict__ btot, int K, int E,
                            int* __restrict__ bstart, int* __restrict__ bcur) {
    __shared__ int waveTot[4];
    __shared__ int waveOff[4];
    int tid = threadIdx.x;
    int lane = tid & 63, wave = tid >> 6;
    int v = (tid < K) ? btot[tid] : 0;
    int s = v;
    #pragma unroll
    for (int o = 1; o < 64; o <<= 1) {
        int t = __shfl_up(s, o);
        if (lane >= o) s += t;
    }
    if (lane == 63) waveTot[wave] = s;
    __syncthreads();
    if (tid == 0) {
        int acc = 0;
        #pragma unroll
        for (int w = 0; w < 4; w++) { waveOff[w] = acc; acc += waveTot[w]; }
    }
    __syncthreads();
    int excl = s - v + waveOff[wave];
    if (tid < K) { bstart[tid] = excl; bcur[tid] = excl; }
    if (tid == 0) bstart[K] = E;
}

// ================= fused: bucket_scatter (LDS counting sort) + GEMM1 =================
// blocks [0,B): LDS hist -> local scan -> reserve global range per bucket (atomicAdd bcur)
//   -> scatter records into LDS sorted by bucket -> stream out in contiguous runs.
//   record = src(u16) | dst<<16  (dst < 2^16; bucket = rec>>24, local = (rec>>16)&255).
// blocks [B,..): MFMA GEMM1 tile (128 rows, 4 waves), Z1 UNSCALED.

template<int K, bool ABF16, bool SCALE>
__device__ __forceinline__ void gemm_body(int blk, int tid, const void* __restrict__ Ap,
                                          const short* __restrict__ Bfrag,
                                          short* __restrict__ C, int M,
                                          const float* __restrict__ dis) {
    int w = tid >> 6;
    int lane = tid & 63;
    int ln = lane & 15;
    int q  = lane >> 4;
    int rowTile = blk * 128 + w * 32;

    int r0 = rowTile + ln;
    int r1 = rowTile + 16 + ln;
    int r0c = (r0 < M) ? r0 : (M - 1);
    int r1c = (r1 < M) ? r1 : (M - 1);

    const float* a0F = (const float*)Ap + (size_t)r0c * K + q * 8;
    const float* a1F = (const float*)Ap + (size_t)r1c * K + q * 8;
    const short* a0B = (const short*)Ap + (size_t)r0c * K + q * 8;
    const short* a1B = (const short*)Ap + (size_t)r1c * K + q * 8;
    const short* bLane = Bfrag + lane * 8;

    floatx4 acc[2][8];
    #pragma unroll
    for (int f = 0; f < 2; f++)
        #pragma unroll
        for (int t = 0; t < 8; t++) acc[f][t] = (floatx4){0.f, 0.f, 0.f, 0.f};

    constexpr int NIT = K / 32;
    #pragma unroll
    for (int kb = 0; kb < NIT; kb++) {
        int kt = kb * 32;
        bf16x8 aF0, aF1;
        if (ABF16) {
            aF0 = *(const bf16x8*)(a0B + kt);
            aF1 = *(const bf16x8*)(a1B + kt);
        } else {
            float4 x0 = *(const float4*)(a0F + kt);
            float4 x1 = *(const float4*)(a0F + kt + 4);
            float4 y0 = *(const float4*)(a1F + kt);
            float4 y1 = *(const float4*)(a1F + kt + 4);
            aF0[0] = f2bf(x0.x); aF0[1] = f2bf(x0.y); aF0[2] = f2bf(x0.z); aF0[3] = f2bf(x0.w);
            aF0[4] = f2bf(x1.x); aF0[5] = f2bf(x1.y); aF0[6] = f2bf(x1.z); aF0[7] = f2bf(x1.w);
            aF1[0] = f2bf(y0.x); aF1[1] = f2bf(y0.y); aF1[2] = f2bf(y0.z); aF1[3] = f2bf(y0.w);
            aF1[4] = f2bf(y1.x); aF1[5] = f2bf(y1.y); aF1[6] = f2bf(y1.z); aF1[7] = f2bf(y1.w);
        }
        bf16x8 bF[8];
        #pragma unroll
        for (int t = 0; t < 8; t++)
            bF[t] = *(const bf16x8*)(bLane + (size_t)(kb * 8 + t) * 512);
        #pragma unroll
        for (int t = 0; t < 8; t++) {
            acc[0][t] = __builtin_amdgcn_mfma_f32_16x16x32_bf16(aF0, bF[t], acc[0][t], 0, 0, 0);
            acc[1][t] = __builtin_amdgcn_mfma_f32_16x16x32_bf16(aF1, bF[t], acc[1][t], 0, 0, 0);
        }
    }

    #pragma unroll
    for (int f = 0; f < 2; f++) {
        #pragma unroll
        for (int reg = 0; reg < 4; reg++) {
            int r = rowTile + f * 16 + q * 4 + reg;
            if (r < M) {
                float s = SCALE ? dis[r] : 1.f;
                #pragma unroll
                for (int t = 0; t < 8; t++)
                    C[(size_t)r * 128 + t * 16 + ln] = f2bf(s * acc[f][t][reg]);
            }
        }
    }
}

__launch_bounds__(256)
__global__ void scatter_gemm1(const int* __restrict__ src, const int* __restrict__ dst,
                              int E, int B, int* __restrict__ bcur,
                              unsigned* __restrict__ bucketed,
                              const float* __restrict__ x, const short* __restrict__ w1f,
                              short* __restrict__ z1, int M) {
    __shared__ int lh[256];
    __shared__ int lofs[256];
    __shared__ int gbase[256];
    __shared__ unsigned srt[EPB];
    __shared__ int waveTot[4];
    __shared__ int waveOff[4];
    int bid = blockIdx.x;
    int tid = threadIdx.x;
    if (bid < B) {
        lh[tid] = 0;
        __syncthreads();
        int lo = bid * EPB, hi = min(lo + EPB, E);
        for (int e = lo + tid; e < hi; e += 256)
            atomicAdd(&lh[dst[e] >> NB_SHIFT], 1);
        __syncthreads();
        int v = lh[tid];
        int lane = tid & 63, wave = tid >> 6;
        int s = v;
        #pragma unroll
        for (int o = 1; o < 64; o <<= 1) {
            int t = __shfl_up(s, o);
            if (lane >= o) s += t;
        }
        if (lane == 63) waveTot[wave] = s;
        __syncthreads();
        if (tid == 0) {
            int acc = 0;
            #pragma unroll
            for (int w = 0; w < 4; w++) { waveOff[w] = acc; acc += waveTot[w]; }
        }
        __syncthreads();
        int excl = s - v + waveOff[wave];
        lofs[tid] = excl;
        if (v) gbase[tid] = atomicAdd(&bcur[tid], v);   // reserve global range
        __syncthreads();
        lh[tid] = excl;                                  // local cursor
        __syncthreads();
        for (int e = lo + tid; e < hi; e += 256) {
            int d = dst[e];
            unsigned rec = (unsigned)(src[e] & 0xFFFF) | ((unsigned)d << 16);
            int p = atomicAdd(&lh[d >> NB_SHIFT], 1);
            srt[p] = rec;
        }
        __syncthreads();
        int cnt = hi - lo;
        for (int p = tid; p < cnt; p += 256) {
            unsigned r = srt[p];
            int k = r >> 24;
            bucketed[gbase[k] + (p - lofs[k])] = r;      // contiguous runs per bucket
        }
    } else {
        gemm_body<256, false, false>(bid - B, tid, (const void*)x, w1f, z1, M, nullptr);
    }
}

// one block per bucket: degrees, row_ptr/row_end/dis, then LDS-staged csr fill (coalesced out).
__global__ void fill_csr_deg(const unsigned* __restrict__ bucketed,
                             const int* __restrict__ bstart,
                             int* __restrict__ row_ptr, int* __restrict__ row_end,
                             float* __restrict__ dis,
                             unsigned short* __restrict__ csr_src, int N) {
    __shared__ int cnt[256];
    __shared__ int rp[256];
    __shared__ int waveTot[4];
    __shared__ int waveOff[4];
    __shared__ unsigned short lcsr[8192];
    int k = blockIdx.x;
    int tid = threadIdx.x;
    int base = k << NB_SHIFT;
    cnt[tid] = 0;
    __syncthreads();
    int lo = bstart[k], hi = bstart[k + 1];
    int m = hi - lo;
    for (int e = lo + tid; e < hi; e += 256)
        atomicAdd(&cnt[(bucketed[e] >> 16) & 255], 1);
    __syncthreads();
    int v = cnt[tid];
    int lane = tid & 63, wave = tid >> 6;
    int s = v;
    #pragma unroll
    for (int o = 1; o < 64; o <<= 1) {
        int t = __shfl_up(s, o);
        if (lane >= o) s += t;
    }
    if (lane == 63) waveTot[wave] = s;
    __syncthreads();
    if (tid == 0) {
        int acc = 0;
        #pragma unroll
        for (int w = 0; w < 4; w++) { waveOff[w] = acc; acc += waveTot[w]; }
    }
    __syncthreads();
    int excl = s - v + waveOff[wave];
    rp[tid] = excl;                      // LOCAL cursor (within bucket)
    int node = base + tid;
    if (node < N) {
        row_ptr[node] = lo + excl;
        row_end[node] = lo + excl + v;
        dis[node] = rsqrtf(1.0f + (float)v);   // self-loop folded into degree
    }
    __syncthreads();
    if (m <= 8192) {
        for (int e = lo + tid; e < hi; e += 256) {
            unsigned sd = bucketed[e];
            int p = atomicAdd(&rp[(sd >> 16) & 255], 1);
            lcsr[p] = (unsigned short)(sd & 0xFFFFu);
        }
        __syncthreads();
        for (int i = tid; i < m; i += 256) csr_src[lo + i] = lcsr[i];
    } else {                              // safety fallback (never hit for bench data)
        for (int e = lo + tid; e < hi; e += 256) {
            unsigned sd = bucketed[e];
            int p = atomicAdd(&rp[(sd >> 16) & 255], 1);
            csr_src[lo + p] = (unsigned short)(sd & 0xFFFFu);
        }
    }
}

// ================= aggregation (one wave/node; chunked index preload + shfl broadcast) ====
// Per 64-edge chunk: one coalesced csr load + one dis gather per wave; inner loop's row
// gathers depend only on a VALU shuffle (no per-edge index/dis loads on the critical path).
// Layer 1: z1 is UNSCALED Z1 bf16; acc += dis[s] * row; out = leaky(dis[d]*acc + b1) -> bf16 h.

__launch_bounds__(256)
__global__ void agg_layer1(const short* __restrict__ z1, const int* __restrict__ row_ptr,
                           const int* __restrict__ row_end,
                           const unsigned short* __restrict__ csr_src,
                           const float* __restrict__ dis, const float* __restrict__ b1,
                           short* __restrict__ h, int N) {
    int wave = threadIdx.x >> 6;
    int node = blockIdx.x * 4 + wave;
    if (node >= N) return;
    int lane = threadIdx.x & 63;
    int qi = lane >> 4;
    int fl = lane & 15;
    int fo = fl * 8;
    const short* zb = z1 + fo;
    int start = row_ptr[node], end = row_end[node];
    float acc[8];
    #pragma unroll
    for (int t = 0; t < 8; t++) acc[t] = 0.f;
    for (int bse = start; bse < end; bse += 64) {
        int n = end - bse; n = (n > 64) ? 64 : n;
        int idx = (int)csr_src[bse + ((lane < n) ? lane : 0)];
        float dl = dis[idx];
        for (int j = 0; j < n; j += 8) {            // wave-uniform trip count
            int j0 = j + qi;
            int j1 = j0 + 4;
            int c0 = (j0 < n) ? j0 : 0;
            int c1 = (j1 < n) ? j1 : 0;
            int s0 = __shfl(idx, c0);
            int s1 = __shfl(idx, c1);
            float d0 = __shfl(dl, c0);
            float d1 = __shfl(dl, c1);
            if (j0 >= n) d0 = 0.f;
            if (j1 >= n) d1 = 0.f;
            bf16x8 z0 = *(const bf16x8*)(zb + (size_t)s0 * 128);
            bf16x8 zv1 = *(const bf16x8*)(zb + (size_t)s1 * 128);
            #pragma unroll
            for (int t = 0; t < 8; t++)
                acc[t] = fmaf(d0, bf2f(z0[t]), fmaf(d1, bf2f(zv1[t]), acc[t]));
        }
    }
    if (qi == 0) {  // self loop, once
        float dn = dis[node];
        bf16x8 zs = *(const bf16x8*)(zb + (size_t)node * 128);
        #pragma unroll
        for (int t = 0; t < 8; t++) acc[t] = fmaf(dn, bf2f(zs[t]), acc[t]);
    }
    #pragma unroll
    for (int t = 0; t < 8; t++) {
        acc[t] += __shfl_xor(acc[t], 16);
        acc[t] += __shfl_xor(acc[t], 32);
    }
    if (qi == 0) {
        float d = dis[node];
        bf16x8 ov;
        #pragma unroll
        for (int t = 0; t < 8; t++) {
            float v = fmaf(d, acc[t], b1[fo + t]);
            v = (v > 0.f) ? v : NEG_SLOPE * v;
            ov[t] = f2bf(v);
        }
        *(bf16x8*)(h + (size_t)node * 128 + fo) = ov;
    }
}

// Layer 2: zp is PRE-SCALED Z2' bf16 (dis applied in gemm2 epilogue); unit-weight adds.

__launch_bounds__(256)
__global__ void agg_layer2(const short* __restrict__ zp, const int* __restrict__ row_ptr,
                           const int* __restrict__ row_end,
                           const unsigned short* __restrict__ csr_src,
                           const float* __restrict__ dis, const float* __restrict__ b_mu,
                           const float* __restrict__ b_lv, float* __restrict__ out, int N) {
    int wave = threadIdx.x >> 6;
    int node = blockIdx.x * 4 + wave;
    if (node >= N) return;
    int lane = threadIdx.x & 63;
    int qi = lane >> 4;
    int fl = lane & 15;
    int fo = fl * 8;
    const short* zb = zp + fo;
    int start = row_ptr[node], end = row_end[node];
    float acc[8];
    #pragma unroll
    for (int t = 0; t < 8; t++) acc[t] = 0.f;
    for (int bse = start; bse < end; bse += 64) {
        int n = end - bse; n = (n > 64) ? 64 : n;
        int idx = (int)csr_src[bse + ((lane < n) ? lane : 0)];
        for (int j = 0; j < n; j += 8) {
            int j0 = j + qi;
            int j1 = j0 + 4;
            int c0 = (j0 < n) ? j0 : 0;
            int c1 = (j1 < n) ? j1 : 0;
            int s0 = __shfl(idx, c0);
            int s1 = __shfl(idx, c1);
            float w0 = (j0 < n) ? 1.f : 0.f;
            float w1 = (j1 < n) ? 1.f : 0.f;
            bf16x8 z0 = *(const bf16x8*)(zb + (size_t)s0 * 128);
            bf16x8 zv1 = *(const bf16x8*)(zb + (size_t)s1 * 128);
            #pragma unroll
            for (int t = 0; t < 8; t++)
                acc[t] = fmaf(w0, bf2f(z0[t]), fmaf(w1, bf2f(zv1[t]), acc[t]));
        }
    }
    if (qi == 0) {
        bf16x8 zs = *(const bf16x8*)(zb + (size_t)node * 128);
        #pragma unroll
        for (int t = 0; t < 8; t++) acc[t] += bf2f(zs[t]);
    }
    #pragma unroll
    for (int t = 0; t < 8; t++) {
        acc[t] += __shfl_xor(acc[t], 16);
        acc[t] += __shfl_xor(acc[t], 32);
    }
    if (qi == 0) {
        float d = dis[node];
        float r[8];
        if (fl < 8) {                        // mu: features fo..fo+7
            #pragma unroll
            for (int t = 0; t < 8; t++) r[t] = fmaf(d, acc[t], b_mu[fo + t]);
            float* p = out + (size_t)node * 64 + fo;
            *(float4*)p       = make_float4(r[0], r[1], r[2], r[3]);
            *(float4*)(p + 4) = make_float4(r[4], r[5], r[6], r[7]);
        } else {                             // logvar: features fo-64..fo-57
            #pragma unroll
            for (int t = 0; t < 8; t++) r[t] = fmaf(d, acc[t], b_lv[fo - 64 + t]);
            float* p = out + (size_t)N * 64 + (size_t)node * 64 + (fo - 64);
            *(float4*)p       = make_float4(r[0], r[1], r[2], r[3]);
            *(float4*)(p + 4) = make_float4(r[4], r[5], r[6], r[7]);
        }
    }
}

// standalone GEMM2 (scaled epilogue)
__launch_bounds__(256)
__global__ void gemm2_kernel(const short* __restrict__ h, const short* __restrict__ wcatf,
                             short* __restrict__ z2, int M, const float* __restrict__ dis) {
    gemm_body<128, true, true>(blockIdx.x, threadIdx.x, (const void*)h, wcatf, z2, M, dis);
}

// ---------------- launcher ----------------

extern "C" void kernel_launch(void* const* d_in, const int* in_sizes, int n_in,
                              void* d_out, int out_size, void* d_ws, size_t ws_size,
                              hipStream_t stream) {
    const float* x   = (const float*)d_in[0];
    const int*   ei  = (const int*)d_in[1];    // [2,E] int32: src then dst
    const float* W1  = (const float*)d_in[2];
    const float* b1  = (const float*)d_in[3];
    const float* Wmu = (const float*)d_in[4];
    const float* bmu = (const float*)d_in[5];
    const float* Wlv = (const float*)d_in[6];
    const float* blv = (const float*)d_in[7];
    float* out = (float*)d_out;

    const int F_IN = 256;
    int N = in_sizes[0] / F_IN;   // 50000 (must be < 65536 for u16 csr)
    int E = in_sizes[1] / 2;      // 800000
    const int* e_src = ei;
    const int* e_dst = ei + E;

    int B = (E + EPB - 1) / EPB;            // edge blocks (~196)
    int K = (N + 255) >> NB_SHIFT;          // dst buckets (~196, <=256)
    int Ggemm = (N + 127) / 128;            // gemm tiles (391)

    char* ws = (char*)d_ws;
    size_t off = 0;
    auto carve = [&](size_t bytes) -> void* {
        void* p = ws + off;
        off += (bytes + 255) & ~(size_t)255;
        return p;
    };
    int*      row_end  = (int*)   carve((size_t)N * 4);
    int*      row_ptr  = (int*)   carve((size_t)N * 4);
    float*    dis      = (float*) carve((size_t)N * 4);
    unsigned short* csr_src = (unsigned short*)carve((size_t)E * 2);
    short*    bufA     = (short*) carve((size_t)N * 128 * 2);  // bf16 Z1 (unscaled), then Z2'
    short*    bufB     = (short*) carve((size_t)N * 128 * 2);  // bf16 h
    short*    w1f      = (short*) carve(128 * 256 * 2);        // bf16 W1 frag-order
    short*    wcatf    = (short*) carve(128 * 128 * 2);        // bf16 [Wmu|Wlv] frag-order
    int*      bstart   = (int*)   carve((size_t)(K + 1) * 4);  // bucket starts
    int*      bcur     = (int*)   carve((size_t)K * 4);        // bucket alloc cursors
    int*      btot     = (int*)   carve((size_t)K * 4);        // bucket totals
    unsigned* bucketed = (unsigned*)carve((size_t)E * 4);      // sorted-by-bucket records

    hipMemsetAsync(btot, 0, (size_t)K * 4, stream);
    // K1: hist (atomic btot) + weight pack
    hipLaunchKernelGGL(hist_pack, dim3(B + 192), dim3(256), 0, stream,
                       e_dst, E, B, K, btot, W1, Wmu, Wlv, w1f, wcatf);
    // tiny single-block scan: bstart/bcur
    hipLaunchKernelGGL(bucket_scan, dim3(1), dim3(256), 0, stream, btot, K, E, bstart, bcur);
    // K3: edge scatter (LDS counting sort, coalesced runs out) + GEMM1
    hipLaunchKernelGGL(scatter_gemm1, dim3(B + Ggemm), dim3(256), 0, stream,
                       e_src, e_dst, E, B, bcur, bucketed, x, w1f, bufA, N);
    hipLaunchKernelGGL(fill_csr_deg, dim3(K), dim3(256), 0, stream,
                       bucketed, bstart, row_ptr, row_end, dis, csr_src, N);
    // h = leaky(dis_d * sum(dis_s * Z1[s]) + b1)
    hipLaunchKernelGGL(agg_layer1, dim3((N + 3) / 4), dim3(256), 0, stream,
                       bufA, row_ptr, row_end, csr_src, dis, b1, bufB, N);
    // Z2' = dis .* (h @ [Wmu|Wlv])
    hipLaunchKernelGGL(gemm2_kernel, dim3(Ggemm), dim3(256), 0, stream,
                       bufB, wcatf, bufA, N, dis);
    hipLaunchKernelGGL(agg_layer2, dim3((N + 3) / 4), dim3(256), 0, stream,
                       bufA, row_ptr, row_end, csr_src, dis, bmu, blv, out, N);
}